// Round 2
// baseline (601.266 us; speedup 1.0000x reference)
//
#include <hip/hip_runtime.h>
#include <hip/hip_bf16.h>

// Problem constants
#define T_IN   16384
#define T_OUT  16376
#define CIN    64
#define NF     64
#define KT     9
#define NB     32
#define TILE   128                 // output rows per tile
#define ROWS   (TILE + KT - 1)     // 136 staged input rows
#define LDS_STRIDE 72              // shorts per row: 64 + 8 pad (144 B, breaks 128B stride)
#define TILES_PER_BATCH 128        // ceil(16376/128); last tile has 120 valid rows
#define NTILES (NB * TILES_PER_BATCH)   // 4096 blocks, one tile each

typedef __bf16 bf16x8 __attribute__((ext_vector_type(8)));
typedef unsigned short u16x8 __attribute__((ext_vector_type(8)));
typedef unsigned short u16x4 __attribute__((ext_vector_type(4)));
typedef float f32x16 __attribute__((ext_vector_type(16)));

// fp32 -> bf16 round-to-nearest-even
__device__ __forceinline__ unsigned short f2bf(float f) {
    unsigned u = __builtin_bit_cast(unsigned, f);
    u += 0x7FFFu + ((u >> 16) & 1u);
    return (unsigned short)(u >> 16);
}

// 4 waves/SIMD requested: VGPR budget 128, LDS 19.5KB -> 4 blocks/CU resident
__global__ __launch_bounds__(256, 4) void conv1d_mfma_kernel(
    const float* __restrict__ x,   // [32][16384][64]
    const float* __restrict__ w,   // [64][9][64]
    const float* __restrict__ b,   // [64]
    float* __restrict__ out)       // [32][16376][64]
{
    __shared__ __attribute__((aligned(16))) unsigned short ldsX[ROWS * LDS_STRIDE];

    const int tid  = threadIdx.x;
    const int lane = tid & 63;
    const int wv   = tid >> 6;        // 4 waves
    const int half = lane >> 5;       // 0/1: k-half of MFMA operand
    const int l31  = lane & 31;
    const int fh   = wv & 1;          // filter half (0: f 0..31, 1: f 32..63)
    const int rh   = wv >> 1;         // row half (0: rows 0..63, 1: rows 64..127)
    const int rbase = rh * 64;
    const int fcol  = fh * 32 + l31;  // this lane's output filter column

    const int g  = blockIdx.x;        // tile id, 0..4095
    const int bb = g >> 7;            // batch
    const int t0 = (g & 127) << 7;    // first output row of tile

    // ---- Kick off staging address calc + loads early ----
    // 136 rows * 16 float4-chunks = 2176 units over 256 threads (8.5 iters)
    // Interleave: issue the x loads first so they overlap the weight loads.
    float4 xv[9];
    int    xr[9], xc[9];
    int nst = 0;
#pragma unroll
    for (int i = 0; i < 9; ++i) {
        const int u = tid + i * 256;
        if (u < ROWS * 16) {
            const int r  = u >> 4;
            const int cg = u & 15;
            int gr = t0 + r;
            gr = gr < (T_IN - 1) ? gr : (T_IN - 1);   // clamp (tail tile only; results discarded)
            xv[i] = *(const float4*)(x + ((size_t)bb * T_IN + gr) * CIN + cg * 4);
            xr[i] = r; xc[i] = cg;
            ++nst;
        }
    }

    // ---- Weight B-fragments into registers ----
    // B layout for mfma_f32_32x32x16_bf16: n = lane&31, k_inner = (lane>>5)*8 + j
    // Global w element: w[f][tap][c], c = s*16 + half*8 + j
    bf16x8 Bf[KT][4];
#pragma unroll
    for (int k = 0; k < KT; ++k) {
#pragma unroll
        for (int s = 0; s < 4; ++s) {
            const float* wp = w + (size_t)fcol * (KT * CIN) + k * CIN + s * 16 + half * 8;
            const float4 w0 = *(const float4*)(wp);
            const float4 w1 = *(const float4*)(wp + 4);
            u16x8 t;
            t[0] = f2bf(w0.x); t[1] = f2bf(w0.y); t[2] = f2bf(w0.z); t[3] = f2bf(w0.w);
            t[4] = f2bf(w1.x); t[5] = f2bf(w1.y); t[6] = f2bf(w1.z); t[7] = f2bf(w1.w);
            Bf[k][s] = __builtin_bit_cast(bf16x8, t);
        }
    }
    const float bias = b[fcol];

    // ---- Commit staged x to LDS (fp32 -> bf16) ----
#pragma unroll
    for (int i = 0; i < 9; ++i) {
        if (i < nst) {
            u16x4 p;
            p[0] = f2bf(xv[i].x); p[1] = f2bf(xv[i].y);
            p[2] = f2bf(xv[i].z); p[3] = f2bf(xv[i].w);
            *(u16x4*)&ldsX[xr[i] * LDS_STRIDE + xc[i] * 4] = p;
        }
    }
    __syncthreads();

    // ---- MFMA main loop ----
    f32x16 acc0 = {0,0,0,0,0,0,0,0,0,0,0,0,0,0,0,0};
    f32x16 acc1 = {0,0,0,0,0,0,0,0,0,0,0,0,0,0,0,0};
    // A-fragment: m = lane&31 (time row), k_inner = half*8+j (channel)
    const int abase = (rbase + l31) * LDS_STRIDE + half * 8;
#pragma unroll
    for (int k = 0; k < KT; ++k) {
#pragma unroll
        for (int s = 0; s < 4; ++s) {
            const int off = abase + k * LDS_STRIDE + s * 16;
            bf16x8 a0 = *(const bf16x8*)&ldsX[off];
            bf16x8 a1 = *(const bf16x8*)&ldsX[off + 32 * LDS_STRIDE];
            acc0 = __builtin_amdgcn_mfma_f32_32x32x16_bf16(a0, Bf[k][s], acc0, 0, 0, 0);
            acc1 = __builtin_amdgcn_mfma_f32_32x32x16_bf16(a1, Bf[k][s], acc1, 0, 0, 0);
        }
    }

    // ---- Epilogue: C/D layout col=lane&31, row=(reg&3)+8*(reg>>2)+4*(lane>>5) ----
#pragma unroll
    for (int m = 0; m < 2; ++m) {
        const f32x16 A = m ? acc1 : acc0;
#pragma unroll
        for (int r = 0; r < 16; ++r) {
            const int tl = rbase + m * 32 + (r & 3) + 8 * (r >> 2) + 4 * half;
            const int tg = t0 + tl;
            if (tg < T_OUT)
                out[((size_t)bb * T_OUT + tg) * NF + fcol] = A[r] + bias;
        }
    }
}

extern "C" void kernel_launch(void* const* d_in, const int* in_sizes, int n_in,
                              void* d_out, int out_size, void* d_ws, size_t ws_size,
                              hipStream_t stream) {
    const float* x = (const float*)d_in[0];
    const float* w = (const float*)d_in[1];
    const float* b = (const float*)d_in[2];
    float* out = (float*)d_out;
    conv1d_mfma_kernel<<<NTILES, 256, 0, stream>>>(x, w, b, out);
}

// Round 3
// 310.307 us; speedup vs baseline: 1.9376x; 1.9376x over previous
//
#include <hip/hip_runtime.h>
#include <hip/hip_bf16.h>

// Problem constants
#define T_IN   16384
#define T_OUT  16376
#define CIN    64
#define NF     64
#define KT     9
#define TILE   128                 // output rows per tile
#define ROWS   (TILE + KT - 1)     // 136 staged input rows
#define LDS_STRIDE 72              // shorts per row: 64 + 8 pad (breaks 128B stride)
#define NBLOCKS 512                // 2 blocks/CU, persistent
#define TILE_ITERS 8               // 512*8 = 4096 tiles = 32 batches * 128 tiles

typedef __bf16 bf16x8 __attribute__((ext_vector_type(8)));
typedef unsigned short u16x8 __attribute__((ext_vector_type(8)));
typedef unsigned short u16x4 __attribute__((ext_vector_type(4)));
typedef float f32x16 __attribute__((ext_vector_type(16)));

// fp32 -> bf16 round-to-nearest-even
__device__ __forceinline__ unsigned short f2bf(float f) {
    unsigned u = __builtin_bit_cast(unsigned, f);
    u += 0x7FFFu + ((u >> 16) & 1u);
    return (unsigned short)(u >> 16);
}

// NOTE: register budget pins this kernel at 2 waves/SIMD (Bf=144 + acc=32 +
// xv=36 live). (256,4) forces spill-to-scratch (R2: 6x HBM traffic). Keep (256,2).
__global__ __launch_bounds__(256, 2) void conv1d_mfma_kernel(
    const float* __restrict__ x,   // [32][16384][64]
    const float* __restrict__ w,   // [64][9][64]
    const float* __restrict__ b,   // [64]
    float* __restrict__ out)       // [32][16376][64]
{
    __shared__ __attribute__((aligned(16))) unsigned short ldsX[2][ROWS * LDS_STRIDE];

    const int tid  = threadIdx.x;
    const int lane = tid & 63;
    const int wv   = tid >> 6;        // 4 waves
    const int half = lane >> 5;       // 0/1: k-half of MFMA operand
    const int l31  = lane & 31;
    const int rbase = (wv >> 1) * 64; // row half (rows 0..63 / 64..127)
    const int fcol  = (wv & 1) * 32 + l31;  // output filter column

    const int g0  = blockIdx.x * TILE_ITERS;  // first tile id of this block
    const int bb  = g0 >> 7;                  // batch (all 8 tiles same batch)
    const int t00 = (g0 & 127) << 7;          // first output row of first tile

    const float* xbase = x + (size_t)bb * T_IN * CIN;

    // ---- Prefetch tile 0 into registers ----
    float4 xv[9];
#pragma unroll
    for (int i = 0; i < 9; ++i) {
        const int u = tid + i * 256;          // 136 rows * 16 float4-chunks = 2176 units
        if (u < ROWS * 16) {
            int gr = t00 + (u >> 4);
            gr = gr < (T_IN - 1) ? gr : (T_IN - 1);   // clamp (tail tile; discarded rows)
            xv[i] = *(const float4*)(xbase + (size_t)gr * CIN + (u & 15) * 4);
        }
    }

    // ---- Weight B-fragments into registers (AGPR-side) ----
    // B layout for mfma_f32_32x32x16_bf16: n = lane&31, k_inner = (lane>>5)*8 + j
    bf16x8 Bf[KT][4];
#pragma unroll
    for (int k = 0; k < KT; ++k) {
#pragma unroll
        for (int s = 0; s < 4; ++s) {
            const float* wp = w + (size_t)fcol * (KT * CIN) + k * CIN + s * 16 + half * 8;
            const float4 w0 = *(const float4*)(wp);
            const float4 w1 = *(const float4*)(wp + 4);
            u16x8 t;
            t[0] = f2bf(w0.x); t[1] = f2bf(w0.y); t[2] = f2bf(w0.z); t[3] = f2bf(w0.w);
            t[4] = f2bf(w1.x); t[5] = f2bf(w1.y); t[6] = f2bf(w1.z); t[7] = f2bf(w1.w);
            Bf[k][s] = __builtin_bit_cast(bf16x8, t);
        }
    }
    const float bias = b[fcol];

    // ---- Commit tile 0 to LDS buffer 0 ----
#pragma unroll
    for (int i = 0; i < 9; ++i) {
        const int u = tid + i * 256;
        if (u < ROWS * 16) {
            u16x4 p;
            p[0] = f2bf(xv[i].x); p[1] = f2bf(xv[i].y);
            p[2] = f2bf(xv[i].z); p[3] = f2bf(xv[i].w);
            *(u16x4*)&ldsX[0][(u >> 4) * LDS_STRIDE + (u & 15) * 4] = p;
        }
    }
    __syncthreads();

    const int abase = (rbase + l31) * LDS_STRIDE + half * 8;

    for (int it = 0; it < TILE_ITERS; ++it) {
        const int cur = it & 1;
        const int t0  = t00 + (it << 7);

        // ---- Issue next tile's global loads (latency hides under MFMA) ----
        if (it + 1 < TILE_ITERS) {
            const int t0n = t0 + TILE;
#pragma unroll
            for (int i = 0; i < 9; ++i) {
                const int u = tid + i * 256;
                if (u < ROWS * 16) {
                    int gr = t0n + (u >> 4);
                    gr = gr < (T_IN - 1) ? gr : (T_IN - 1);
                    xv[i] = *(const float4*)(xbase + (size_t)gr * CIN + (u & 15) * 4);
                }
            }
        }

        // ---- MFMA main loop on ldsX[cur] ----
        f32x16 acc0 = {0,0,0,0,0,0,0,0,0,0,0,0,0,0,0,0};
        f32x16 acc1 = {0,0,0,0,0,0,0,0,0,0,0,0,0,0,0,0};
#pragma unroll
        for (int k = 0; k < KT; ++k) {
#pragma unroll
            for (int s = 0; s < 4; ++s) {
                const int off = abase + k * LDS_STRIDE + s * 16;
                bf16x8 a0 = *(const bf16x8*)&ldsX[cur][off];
                bf16x8 a1 = *(const bf16x8*)&ldsX[cur][off + 32 * LDS_STRIDE];
                acc0 = __builtin_amdgcn_mfma_f32_32x32x16_bf16(a0, Bf[k][s], acc0, 0, 0, 0);
                acc1 = __builtin_amdgcn_mfma_f32_32x32x16_bf16(a1, Bf[k][s], acc1, 0, 0, 0);
            }
        }

        // ---- Commit next tile to the other buffer, then one barrier ----
        if (it + 1 < TILE_ITERS) {
#pragma unroll
            for (int i = 0; i < 9; ++i) {
                const int u = tid + i * 256;
                if (u < ROWS * 16) {
                    u16x4 p;
                    p[0] = f2bf(xv[i].x); p[1] = f2bf(xv[i].y);
                    p[2] = f2bf(xv[i].z); p[3] = f2bf(xv[i].w);
                    *(u16x4*)&ldsX[1 - cur][(u >> 4) * LDS_STRIDE + (u & 15) * 4] = p;
                }
            }
            __syncthreads();
        }

        // ---- Epilogue (after barrier: stores drain under next tile's MFMA) ----
        // C/D layout: col=lane&31, row=(reg&3)+8*(reg>>2)+4*(lane>>5)
#pragma unroll
        for (int m = 0; m < 2; ++m) {
            const f32x16 A = m ? acc1 : acc0;
#pragma unroll
            for (int r = 0; r < 16; ++r) {
                const int tl = rbase + m * 32 + (r & 3) + 8 * (r >> 2) + 4 * half;
                const int tg = t0 + tl;
                if (tg < T_OUT)
                    out[((size_t)bb * T_OUT + tg) * NF + fcol] = A[r] + bias;
            }
        }
    }
}

extern "C" void kernel_launch(void* const* d_in, const int* in_sizes, int n_in,
                              void* d_out, int out_size, void* d_ws, size_t ws_size,
                              hipStream_t stream) {
    const float* x = (const float*)d_in[0];
    const float* w = (const float*)d_in[1];
    const float* b = (const float*)d_in[2];
    float* out = (float*)d_out;
    conv1d_mfma_kernel<<<NBLOCKS, 256, 0, stream>>>(x, w, b, out);
}